// Round 10
// baseline (383.266 us; speedup 1.0000x reference)
//
#include <hip/hip_runtime.h>

// CRF loss, S=512, B=256, L=128; out = sum_b log_z_b - gold.
//
// R10: TWO independent scan chains per wave (8 blocks x 64 threads, chains =
// batch groups 2gb, 2gb+1). Per iteration: 16 independent MFMAs
// (mfma_scale_f32_16x16x128_f8f6f4, K=128) issued back-to-back, then the two
// VALU tails. Chain-dependency latency (the R9 limiter, ~165 cyc/step
// exposed) hides under the other chain's issue stream.
//
// Per-step scale: NO max-reduce (R9 scheme, verified absmax 0.0):
//   x rows prenormalized (xh = exp(emit)*2^-X, row max in [1,2), X int32);
//   ac spread across j <= maxE/minE ~ 2.3 => scale byte = 250 - e(ac00),
//   4-bit margin; e5m2 state, e4m3 A; scale applied via MFMA B-scale operand.
//   L (per-batch log2 scale) accumulates X_t + (127 - scale_byte).
//
// Layouts (R5-R9 verified): B byte e=4d+c of dword d holds k~=32g+4d+c;
// D tile d reg r (j=16d+4g+r) stores at byte 4d+r; A[j][k~] =
// exp(T[pi^-1(k~)][j]), pi^-1(32g'+4d+c)=16d+4g'+c.
//
// Chain state uses token-pasted names (Bq0/Bq1, xf0/xf1, ...) so every
// register access is compile-time-indexed (rule #20: no scratch).
//
// Fallbacks: [ws >= xh+X: fast2] [ws >= xs: R8 exact-max, proven] [else bf16].

#define LOG2E 1.4426950408889634f
#define LN2F  0.6931471805599453f

typedef float        f32x4  __attribute__((ext_vector_type(4)));
typedef int          i32x8  __attribute__((ext_vector_type(8)));
typedef unsigned int u32x4  __attribute__((ext_vector_type(4)));
typedef short        bf16x8 __attribute__((ext_vector_type(8)));
typedef __bf16       bf16x2 __attribute__((ext_vector_type(2)));

__device__ __forceinline__ unsigned packbf2(float lo, float hi) {
    bf16x2 p = { (__bf16)lo, (__bf16)hi };   // RNE -> v_cvt_pk_bf16_f32
    return __builtin_bit_cast(unsigned, p);
}

// ================= xs prenormalize kernel =================
// Row (t,b) of 128: xh = exp(emit)*2^-X with row max in [1,2); X[b][t] int.
__global__ __launch_bounds__(256) void crf_xsn_kernel(
    const float* __restrict__ emit, float* __restrict__ xh,
    int* __restrict__ X)
{
    const int tid = threadIdx.x;
    const int r   = blockIdx.x * 16 + (tid >> 4);   // row index = t*256 + b
    const int s   = tid & 15;
    const float4* src = (const float4*)emit + (size_t)r * 32 + s * 2;
    float4 e0 = src[0], e1 = src[1];
    float x0 = __builtin_amdgcn_exp2f(e0.x * LOG2E);
    float x1 = __builtin_amdgcn_exp2f(e0.y * LOG2E);
    float x2 = __builtin_amdgcn_exp2f(e0.z * LOG2E);
    float x3 = __builtin_amdgcn_exp2f(e0.w * LOG2E);
    float x4 = __builtin_amdgcn_exp2f(e1.x * LOG2E);
    float x5 = __builtin_amdgcn_exp2f(e1.y * LOG2E);
    float x6 = __builtin_amdgcn_exp2f(e1.z * LOG2E);
    float x7 = __builtin_amdgcn_exp2f(e1.w * LOG2E);
    float m = fmaxf(fmaxf(fmaxf(x0, x1), fmaxf(x2, x3)),
                    fmaxf(fmaxf(x4, x5), fmaxf(x6, x7)));
#pragma unroll
    for (int off = 1; off < 16; off <<= 1)
        m = fmaxf(m, __shfl_xor(m, off));
    const int eb = (__float_as_int(m) >> 23) & 0xFF;
    const float scl = __int_as_float((254 - eb) << 23);   // 2^(127-eb)
    float4 o0, o1;
    o0.x = x0 * scl; o0.y = x1 * scl; o0.z = x2 * scl; o0.w = x3 * scl;
    o1.x = x4 * scl; o1.y = x5 * scl; o1.z = x6 * scl; o1.w = x7 * scl;
    float4* dst = (float4*)xh + (size_t)r * 32 + s * 2;
    dst[0] = o0; dst[1] = o1;
    if (s == 0) X[(r & 255) * 512 + (r >> 8)] = eb - 127;  // X[b][t]
}

// ================= R10 dual-chain fast scan =================
#define MFMAX(Aop, Bop, SCL) \
    __builtin_amdgcn_mfma_scale_f32_16x16x128_f8f6f4( \
        Aop, Bop, zero4, 0, 1, 0, 0x7F7F7F7F, 0, SCL)

// Per-chain tail: scale estimate, vv, prefetch, cvt->Bq. C is a literal 0/1.
#define TAILC(C, AC, SLOT, TPF, DOPF, LAST) do {                              \
    float a00 = __shfl(AC[0][0], b);                                          \
    int ea = (__float_as_int(a00) >> 23) & 0xFF;                              \
    int sb = 250 - ea;                                                        \
    sb = sb < 1 ? 1 : (sb > 254 ? 254 : sb);                                  \
    L##C += Xs##C[SLOT];                                                      \
    if (!(LAST)) { L##C += 127 - sb; sclw##C = sb * 0x01010101; }             \
    f32x4 vv[8];                                                              \
    _Pragma("unroll") for (int jt = 0; jt < 8; ++jt)                          \
        vv[jt] = AC[jt] * xf##C[SLOT][jt];                                    \
    if (DOPF) {                                                               \
        int tp = (TPF); if (tp > 511) tp = 511;                               \
        _Pragma("unroll") for (int jt = 0; jt < 8; ++jt)                      \
            xf##C[SLOT][jt] = xhf[8192 * tp + lb##C + 4 * jt];                \
        Xs##C[SLOT] = Xi##C[tp];                                              \
    }                                                                         \
    if (LAST) {                                                               \
        fin##C = 0.f;                                                         \
        _Pragma("unroll") for (int jt = 0; jt < 8; ++jt)                      \
            fin##C += (vv[jt][0] + vv[jt][1]) + (vv[jt][2] + vv[jt][3]);      \
    } else {                                                                  \
        _Pragma("unroll") for (int d = 0; d < 8; ++d) {                       \
            int bw = __builtin_amdgcn_cvt_pk_bf8_f32(vv[d][0], vv[d][1], 0, false); \
            Bq##C[d] = __builtin_amdgcn_cvt_pk_bf8_f32(vv[d][2], vv[d][3], bw, true); \
        }                                                                     \
    }                                                                         \
} while (0)

// One iteration = one step of EACH chain. Both MFMA clusters issue first.
#define STEP2(SLOT, TPF, DOPF, LAST) do {                                     \
    f32x4 acA[8], acB[8];                                                     \
    _Pragma("unroll") for (int jt = 0; jt < 8; ++jt)                          \
        acA[jt] = MFMAX(Afr[jt], Bq0, sclw0);                                 \
    _Pragma("unroll") for (int jt = 0; jt < 8; ++jt)                          \
        acB[jt] = MFMAX(Afr[jt], Bq1, sclw1);                                 \
    TAILC(0, acA, SLOT, TPF, DOPF, LAST);                                     \
    TAILC(1, acB, SLOT, TPF, DOPF, LAST);                                     \
} while (0)

__global__ __launch_bounds__(64, 1) void crf_scan_fast2_kernel(
    const float* __restrict__ xh,
    const int*   __restrict__ X,
    const float* __restrict__ Tm,
    float* __restrict__ scan_part)   // (256)
{
    const int gb = blockIdx.x;       // 0..7: chains 2gb (A) and 2gb+1 (B)
    const int l  = threadIdx.x;      // 0..63
    const int b  = l & 15;           // batch within group (MFMA m/n index)
    const int g  = l >> 4;           // 16-lane group (k-block index)
    const int bg0 = gb * 32 + b;
    const int bg1 = bg0 + 16;
    const int lb0 = 32 * bg0 + g;    // per-lane float4 base index, chain A
    const int lb1 = 32 * bg1 + g;    // chain B

    const f32x4* xhf = (const f32x4*)xh;
    const int*   Xi0 = X + bg0 * 512;
    const int*   Xi1 = X + bg1 * 512;
    const f32x4 zero4 = {0.f, 0.f, 0.f, 0.f};

    // ---- constant A (e4m3), shared by both chains ----
    i32x8 Afr[8];
#pragma unroll
    for (int jt = 0; jt < 8; ++jt)
#pragma unroll
        for (int d = 0; d < 8; ++d) {
            const int col = 16 * jt + b;
            const int rb  = 16 * d + 4 * g;
            float a0 = __builtin_amdgcn_exp2f(Tm[(rb + 0) * 128 + col] * LOG2E);
            float a1 = __builtin_amdgcn_exp2f(Tm[(rb + 1) * 128 + col] * LOG2E);
            float a2 = __builtin_amdgcn_exp2f(Tm[(rb + 2) * 128 + col] * LOG2E);
            float a3 = __builtin_amdgcn_exp2f(Tm[(rb + 3) * 128 + col] * LOG2E);
            int w = __builtin_amdgcn_cvt_pk_fp8_f32(a0, a1, 0, false);
            Afr[jt][d] = __builtin_amdgcn_cvt_pk_fp8_f32(a2, a3, w, true);
        }

    // ---- t=0 init both chains: Bq = cvt_bf8(xh[0]); scale 2^-4 ----
    i32x8 Bq0, Bq1;
    int L0, L1;
    int sclw0 = 123 * 0x01010101;
    int sclw1 = 123 * 0x01010101;
    {
        f32x4 x0[8], x1[8];
#pragma unroll
        for (int jt = 0; jt < 8; ++jt) { x0[jt] = xhf[lb0 + 4 * jt];
                                         x1[jt] = xhf[lb1 + 4 * jt]; }
#pragma unroll
        for (int d = 0; d < 8; ++d) {
            int bw0 = __builtin_amdgcn_cvt_pk_bf8_f32(x0[d][0], x0[d][1], 0, false);
            Bq0[d]  = __builtin_amdgcn_cvt_pk_bf8_f32(x0[d][2], x0[d][3], bw0, true);
            int bw1 = __builtin_amdgcn_cvt_pk_bf8_f32(x1[d][0], x1[d][1], 0, false);
            Bq1[d]  = __builtin_amdgcn_cvt_pk_bf8_f32(x1[d][2], x1[d][3], bw1, true);
        }
        L0 = Xi0[0] + 4;
        L1 = Xi1[0] + 4;
    }

    // ---- prefetch t = 1..4 into 4 slots, both chains ----
    f32x4 xf0[4][8], xf1[4][8];
    int   Xs0[4], Xs1[4];
#pragma unroll
    for (int k = 0; k < 4; ++k) {
#pragma unroll
        for (int jt = 0; jt < 8; ++jt) {
            xf0[k][jt] = xhf[8192 * (1 + k) + lb0 + 4 * jt];
            xf1[k][jt] = xhf[8192 * (1 + k) + lb1 + 4 * jt];
        }
        Xs0[k] = Xi0[1 + k];
        Xs1[k] = Xi1[1 + k];
    }

    float fin0 = 0.f, fin1 = 0.f;

    // ---- main loop: t = 1..508 (127 groups of 4) ----
#pragma unroll 1
    for (int grp = 0; grp < 127; ++grp) {
        const int t0 = 1 + 4 * grp;
        STEP2(0, t0 + 4, 1, 0);
        STEP2(1, t0 + 5, 1, 0);
        STEP2(2, t0 + 6, 1, 0);
        STEP2(3, t0 + 7, 1, 0);
    }
    // tail: t = 509, 510, 511 (slots 0,1,2)
    STEP2(0, 0, 0, 0);
    STEP2(1, 0, 0, 0);
    STEP2(2, 0, 0, 1);

    // ---- finalize both chains ----
    fin0 += __shfl_xor(fin0, 16);
    fin0 += __shfl_xor(fin0, 32);
    fin1 += __shfl_xor(fin1, 16);
    fin1 += __shfl_xor(fin1, 32);
    if (l < 16) {
        scan_part[gb * 32 + l]      = ((float)L0 + __log2f(fin0)) * LN2F;
        scan_part[gb * 32 + 16 + l] = ((float)L1 + __log2f(fin1)) * LN2F;
    }
}

// ================= R8 exact-max scan (proven; middle fallback) ============
#define STEPM(SLOT, TPF, DOPF, LAST) do {                                     \
    f32x4 ac[8];                                                              \
    _Pragma("unroll") for (int jt = 0; jt < 8; ++jt)                          \
        ac[jt] = __builtin_amdgcn_mfma_scale_f32_16x16x128_f8f6f4(            \
            Afr[jt], Bq, zero4, 0, 1, 0, 0x7F7F7F7F, 0, sclw);                \
    float vv[8][4];                                                           \
    _Pragma("unroll") for (int jt = 0; jt < 8; ++jt) {                        \
        f32x4 xw = xf[SLOT][jt];                                              \
        vv[jt][0] = ac[jt][0] * xw[0];                                        \
        vv[jt][1] = ac[jt][1] * xw[1];                                        \
        vv[jt][2] = ac[jt][2] * xw[2];                                        \
        vv[jt][3] = ac[jt][3] * xw[3];                                        \
    }                                                                         \
    if (DOPF) {                                                               \
        int tp = (TPF); if (tp > 511) tp = 511;                               \
        _Pragma("unroll") for (int jt = 0; jt < 8; ++jt)                      \
            xf[SLOT][jt] = xsf[8192 * tp + lb + 4 * jt];                      \
    }                                                                         \
    if (LAST) {                                                               \
        fin = 0.f;                                                            \
        _Pragma("unroll") for (int jt = 0; jt < 8; ++jt)                      \
            fin += (vv[jt][0] + vv[jt][1]) + (vv[jt][2] + vv[jt][3]);         \
    } else {                                                                  \
        float m8[8];                                                          \
        _Pragma("unroll") for (int jt = 0; jt < 8; ++jt)                      \
            m8[jt] = fmaxf(fmaxf(vv[jt][0], vv[jt][1]),                       \
                           fmaxf(vv[jt][2], vv[jt][3]));                      \
        float mx = fmaxf(fmaxf(fmaxf(m8[0], m8[1]), fmaxf(m8[2], m8[3])),     \
                         fmaxf(fmaxf(m8[4], m8[5]), fmaxf(m8[6], m8[7])));    \
        mx = fmaxf(mx, __shfl_xor(mx, 16));                                   \
        mx = fmaxf(mx, __shfl_xor(mx, 32));                                   \
        int Ee = (__float_as_int(mx) >> 23) & 0xFF;                           \
        if (Ee < 16)  Ee = 16;                                                \
        if (Ee > 250) Ee = 250;                                               \
        ls2 += Ee - 125;                                                      \
        sclw = (252 - Ee) * 0x01010101;                                       \
        _Pragma("unroll") for (int d = 0; d < 8; ++d) {                       \
            int bw = __builtin_amdgcn_cvt_pk_bf8_f32(vv[d][0], vv[d][1], 0, false); \
            Bq[d]  = __builtin_amdgcn_cvt_pk_bf8_f32(vv[d][2], vv[d][3], bw, true); \
        }                                                                     \
    }                                                                         \
} while (0)

__global__ __launch_bounds__(256) void crf_xs32_kernel(
    const float* __restrict__ emit, float* __restrict__ xs)
{
    const size_t i = (size_t)blockIdx.x * 256 + threadIdx.x;
    const float4 e = ((const float4*)emit)[i];
    float4 o;
    o.x = __builtin_amdgcn_exp2f(e.x * LOG2E);
    o.y = __builtin_amdgcn_exp2f(e.y * LOG2E);
    o.z = __builtin_amdgcn_exp2f(e.z * LOG2E);
    o.w = __builtin_amdgcn_exp2f(e.w * LOG2E);
    ((float4*)xs)[i] = o;
}

__global__ __launch_bounds__(64, 1) void crf_scan_mx_kernel(
    const float* __restrict__ emit,
    const float* __restrict__ xs,
    const float* __restrict__ Tm,
    float* __restrict__ scan_part)
{
    const int gb = blockIdx.x;
    const int l  = threadIdx.x;
    const int b  = l & 15;
    const int g  = l >> 4;
    const int bg = gb * 16 + b;
    const int lb = 32 * bg + g;

    const f32x4* xsf = (const f32x4*)xs;
    const f32x4 zero4 = {0.f, 0.f, 0.f, 0.f};

    i32x8 Afr[8];
#pragma unroll
    for (int jt = 0; jt < 8; ++jt)
#pragma unroll
        for (int d = 0; d < 8; ++d) {
            const int col = 16 * jt + b;
            const int rb  = 16 * d + 4 * g;
            float a0 = __builtin_amdgcn_exp2f(Tm[(rb + 0) * 128 + col] * LOG2E);
            float a1 = __builtin_amdgcn_exp2f(Tm[(rb + 1) * 128 + col] * LOG2E);
            float a2 = __builtin_amdgcn_exp2f(Tm[(rb + 2) * 128 + col] * LOG2E);
            float a3 = __builtin_amdgcn_exp2f(Tm[(rb + 3) * 128 + col] * LOG2E);
            int w = __builtin_amdgcn_cvt_pk_fp8_f32(a0, a1, 0, false);
            Afr[jt][d] = __builtin_amdgcn_cvt_pk_fp8_f32(a2, a3, w, true);
        }

    i32x8 Bq;
    int ls2 = 0;
    int sclw;
    {
        float x0[8][4];
#pragma unroll
        for (int jt = 0; jt < 8; ++jt) {
            float4 e = ((const float4*)emit)[lb + 4 * jt];
            x0[jt][0] = __builtin_amdgcn_exp2f(e.x * LOG2E);
            x0[jt][1] = __builtin_amdgcn_exp2f(e.y * LOG2E);
            x0[jt][2] = __builtin_amdgcn_exp2f(e.z * LOG2E);
            x0[jt][3] = __builtin_amdgcn_exp2f(e.w * LOG2E);
        }
        float m8[8];
#pragma unroll
        for (int jt = 0; jt < 8; ++jt)
            m8[jt] = fmaxf(fmaxf(x0[jt][0], x0[jt][1]),
                           fmaxf(x0[jt][2], x0[jt][3]));
        float mx = fmaxf(fmaxf(fmaxf(m8[0], m8[1]), fmaxf(m8[2], m8[3])),
                         fmaxf(fmaxf(m8[4], m8[5]), fmaxf(m8[6], m8[7])));
        mx = fmaxf(mx, __shfl_xor(mx, 16));
        mx = fmaxf(mx, __shfl_xor(mx, 32));
        int Ee = (__float_as_int(mx) >> 23) & 0xFF;
        if (Ee < 16)  Ee = 16;
        if (Ee > 250) Ee = 250;
        ls2 += Ee - 125;
        sclw = (252 - Ee) * 0x01010101;
#pragma unroll
        for (int d = 0; d < 8; ++d) {
            int bw = __builtin_amdgcn_cvt_pk_bf8_f32(x0[d][0], x0[d][1], 0, false);
            Bq[d]  = __builtin_amdgcn_cvt_pk_bf8_f32(x0[d][2], x0[d][3], bw, true);
        }
    }

    f32x4 xf[4][8];
#pragma unroll
    for (int k = 0; k < 4; ++k)
#pragma unroll
        for (int jt = 0; jt < 8; ++jt)
            xf[k][jt] = xsf[8192 * (1 + k) + lb + 4 * jt];

    float fin = 0.f;

#pragma unroll 1
    for (int grp = 0; grp < 127; ++grp) {
        const int t0 = 1 + 4 * grp;
        STEPM(0, t0 + 4, 1, 0);
        STEPM(1, t0 + 5, 1, 0);
        STEPM(2, t0 + 6, 1, 0);
        STEPM(3, t0 + 7, 1, 0);
    }
    STEPM(0, 0, 0, 0);
    STEPM(1, 0, 0, 0);
    STEPM(2, 0, 0, 1);

    fin += __shfl_xor(fin, 16);
    fin += __shfl_xor(fin, 32);
    if (l < 16)
        scan_part[gb * 16 + l] = ((float)ls2 + __log2f(fin)) * LN2F;
}

// ================= bf16 fallback scan (R7 structure) =================
#define MFMAB(Aop, Bop, Cop) \
    __builtin_amdgcn_mfma_f32_16x16x32_bf16( \
        __builtin_bit_cast(bf16x8, Aop), __builtin_bit_cast(bf16x8, Bop), Cop, 0, 0, 0)

#define STEPB(SLOT, TPF, DOPF, RN, LAST) do {                                 \
    f32x4 ac[8];                                                              \
    _Pragma("unroll") for (int jt = 0; jt < 8; ++jt)                          \
        ac[jt] = MFMAB(Afr[0][jt], Bf[0], zero4);                             \
    _Pragma("unroll") for (int ch = 1; ch < 4; ++ch)                          \
        _Pragma("unroll") for (int jt = 0; jt < 8; ++jt)                      \
            ac[jt] = MFMAB(Afr[ch][jt], Bf[ch], ac[jt]);                      \
    float xv[8][4];                                                           \
    _Pragma("unroll") for (int jt = 0; jt < 8; ++jt) {                        \
        float4 xw = xbf[SLOT][jt];                                            \
        xv[jt][0] = __builtin_amdgcn_exp2f(xw.x * LOG2E);                     \
        xv[jt][1] = __builtin_amdgcn_exp2f(xw.y * LOG2E);                     \
        xv[jt][2] = __builtin_amdgcn_exp2f(xw.z * LOG2E);                     \
        xv[jt][3] = __builtin_amdgcn_exp2f(xw.w * LOG2E);                     \
    }                                                                         \
    if (DOPF) {                                                               \
        int tp = (TPF); if (tp > 511) tp = 511;                               \
        _Pragma("unroll") for (int jt = 0; jt < 8; ++jt)                      \
            xbf[SLOT][jt] = emf4[8192 * tp + lb + 4 * jt];                    \
    }                                                                         \
    float vv[8][4];                                                           \
    _Pragma("unroll") for (int jt = 0; jt < 8; ++jt)                          \
        _Pragma("unroll") for (int r = 0; r < 4; ++r)                         \
            vv[jt][r] = ac[jt][r] * xv[jt][r];                                \
    if (RN) {                                                                 \
        float mx = vv[0][0];                                                  \
        _Pragma("unroll") for (int jt = 0; jt < 8; ++jt)                      \
            _Pragma("unroll") for (int r = 0; r < 4; ++r)                     \
                mx = fmaxf(mx, vv[jt][r]);                                    \
        mx = fmaxf(mx, __shfl_xor(mx, 16));                                   \
        mx = fmaxf(mx, __shfl_xor(mx, 32));                                   \
        int Ee = (__float_as_int(mx) >> 23) & 0xFF;                           \
        if (Ee > 254) Ee = 254;                                               \
        ls2 += Ee - 127;                                                      \
        float scl = __int_as_float((254 - Ee) << 23);                         \
        _Pragma("unroll") for (int jt = 0; jt < 8; ++jt)                      \
            _Pragma("unroll") for (int r = 0; r < 4; ++r)                     \
                vv[jt][r] *= scl;                                             \
    }                                                                         \
    if (LAST) {                                                               \
        fin = 0.f;                                                            \
        _Pragma("unroll") for (int jt = 0; jt < 8; ++jt)                      \
            fin += (vv[jt][0] + vv[jt][1]) + (vv[jt][2] + vv[jt][3]);         \
    } else {                                                                  \
        _Pragma("unroll") for (int ch = 0; ch < 4; ++ch) {                    \
            Bf[ch][0] = packbf2(vv[2*ch][0],     vv[2*ch][1]);                \
            Bf[ch][1] = packbf2(vv[2*ch][2],     vv[2*ch][3]);                \
            Bf[ch][2] = packbf2(vv[2*ch + 1][0], vv[2*ch + 1][1]);            \
            Bf[ch][3] = packbf2(vv[2*ch + 1][2], vv[2*ch + 1][3]);            \
        }                                                                     \
    }                                                                         \
} while (0)

__global__ __launch_bounds__(64, 1) void crf_scan_bf16_kernel(
    const float* __restrict__ emit,
    const float* __restrict__ Tm,
    float* __restrict__ scan_part)
{
    const int gb = blockIdx.x;
    const int l  = threadIdx.x;
    const int b  = l & 15;
    const int g  = l >> 4;
    const int bg = gb * 16 + b;
    const int lb = 32 * bg + g;

    const float4* emf4 = (const float4*)emit;
    const f32x4 zero4 = {0.f, 0.f, 0.f, 0.f};

    u32x4 Afr[4][8];
#pragma unroll
    for (int ch = 0; ch < 4; ++ch)
#pragma unroll
        for (int p = 0; p < 4; ++p) {
            const int e0 = 2 * p, e1 = 2 * p + 1;
            const int jp0 = 32 * ch + 16 * (e0 >> 2) + 4 * g + (e0 & 3);
            const int jp1 = 32 * ch + 16 * (e1 >> 2) + 4 * g + (e1 & 3);
#pragma unroll
            for (int jt = 0; jt < 8; ++jt) {
                float a0 = __builtin_amdgcn_exp2f(Tm[jp0 * 128 + 16 * jt + b] * LOG2E);
                float a1 = __builtin_amdgcn_exp2f(Tm[jp1 * 128 + 16 * jt + b] * LOG2E);
                Afr[ch][jt][p] = packbf2(a0, a1);
            }
        }

    u32x4 Bf[4];
    {
        float x0[8][4];
#pragma unroll
        for (int jt = 0; jt < 8; ++jt) {
            float4 e = emf4[lb + 4 * jt];
            x0[jt][0] = __builtin_amdgcn_exp2f(e.x * LOG2E);
            x0[jt][1] = __builtin_amdgcn_exp2f(e.y * LOG2E);
            x0[jt][2] = __builtin_amdgcn_exp2f(e.z * LOG2E);
            x0[jt][3] = __builtin_amdgcn_exp2f(e.w * LOG2E);
        }
#pragma unroll
        for (int ch = 0; ch < 4; ++ch) {
            Bf[ch][0] = packbf2(x0[2 * ch][0],     x0[2 * ch][1]);
            Bf[ch][1] = packbf2(x0[2 * ch][2],     x0[2 * ch][3]);
            Bf[ch][2] = packbf2(x0[2 * ch + 1][0], x0[2 * ch + 1][1]);
            Bf[ch][3] = packbf2(x0[2 * ch + 1][2], x0[2 * ch + 1][3]);
        }
    }

    float4 xbf[4][8];
#pragma unroll
    for (int k = 0; k < 4; ++k)
#pragma unroll
        for (int jt = 0; jt < 8; ++jt)
            xbf[k][jt] = emf4[8192 * (1 + k) + lb + 4 * jt];

    int ls2 = 0;
    float fin = 0.f;

#pragma unroll 1
    for (int grp = 0; grp < 63; ++grp) {
        const int t0 = 1 + 8 * grp;
        STEPB(0, t0 + 4,  1, 0, 0);
        STEPB(1, t0 + 5,  1, 0, 0);
        STEPB(2, t0 + 6,  1, 0, 0);
        STEPB(3, t0 + 7,  1, 0, 0);
        STEPB(0, t0 + 8,  1, 0, 0);
        STEPB(1, t0 + 9,  1, 0, 0);
        STEPB(2, t0 + 10, 1, 0, 0);
        STEPB(3, t0 + 11, 1, 1, 0);
    }
    STEPB(0, 509, 1, 0, 0);
    STEPB(1, 510, 1, 0, 0);
    STEPB(2, 511, 1, 0, 0);
    STEPB(3, 0,   0, 0, 0);
    STEPB(0, 0,   0, 0, 0);
    STEPB(1, 0,   0, 0, 0);
    STEPB(2, 0,   0, 0, 1);

    fin += __shfl_xor(fin, 16);
    fin += __shfl_xor(fin, 32);
    if (l < 16)
        scan_part[gb * 16 + l] = ((float)ls2 + __log2f(fin)) * LN2F;
}

// ================= gold + final =================
__global__ __launch_bounds__(256) void crf_gold_kernel(
    const float* __restrict__ emit, const float* __restrict__ Tm,
    const int* __restrict__ labels, const int* __restrict__ startp,
    float* __restrict__ gold_part)
{
    const int b = blockIdx.x, tid = threadIdx.x;
    __shared__ int lab[512];
    __shared__ float r[4];
    lab[tid]       = labels[b * 512 + tid];
    lab[tid + 256] = labels[b * 512 + tid + 256];
    __syncthreads();
    float s = 0.f;
    {
        int y0 = lab[tid];
        int p0 = (tid == 0) ? startp[0] : lab[tid - 1];
        s += emit[((size_t)tid * 256 + b) * 128 + y0] + Tm[p0 * 128 + y0];
        int t1 = tid + 256;
        int y1 = lab[t1];
        int p1 = lab[t1 - 1];
        s += emit[((size_t)t1 * 256 + b) * 128 + y1] + Tm[p1 * 128 + y1];
    }
#pragma unroll
    for (int off = 1; off < 64; off <<= 1) s += __shfl_xor(s, off);
    if ((tid & 63) == 0) r[tid >> 6] = s;
    __syncthreads();
    if (tid == 0) gold_part[b] = (r[0] + r[1]) + (r[2] + r[3]);
}

__global__ __launch_bounds__(256) void crf_final_kernel(
    const float* __restrict__ scan_part, const float* __restrict__ gold_part,
    float* __restrict__ out)
{
    const int tid = threadIdx.x;
    __shared__ float r[4];
    float v = scan_part[tid] - gold_part[tid];
#pragma unroll
    for (int off = 1; off < 64; off <<= 1) v += __shfl_xor(v, off);
    if ((tid & 63) == 0) r[tid >> 6] = v;
    __syncthreads();
    if (tid == 0) out[0] = (r[0] + r[1]) + (r[2] + r[3]);
}

extern "C" void kernel_launch(void* const* d_in, const int* in_sizes, int n_in,
                              void* d_out, int out_size, void* d_ws, size_t ws_size,
                              hipStream_t stream) {
    const float* emit   = (const float*)d_in[0];
    const float* Tm     = (const float*)d_in[1];
    const int*   labels = (const int*)d_in[2];
    const int*   startp = (const int*)d_in[3];

    const size_t xh_bytes = (size_t)512 * 256 * 128 * 4;   // 67,108,864
    const size_t X_bytes  = (size_t)256 * 512 * 4;         // 524,288

    if (ws_size >= xh_bytes + X_bytes + 2048) {
        float* xh        = (float*)d_ws;
        int*   X         = (int*)((char*)d_ws + xh_bytes);
        float* scan_part = (float*)((char*)d_ws + xh_bytes + X_bytes);
        float* gold_part = scan_part + 256;
        crf_xsn_kernel<<<8192, 256, 0, stream>>>(emit, xh, X);
        crf_scan_fast2_kernel<<<8, 64, 0, stream>>>(xh, X, Tm, scan_part);
        crf_gold_kernel<<<256, 256, 0, stream>>>(emit, Tm, labels, startp, gold_part);
        crf_final_kernel<<<1, 256, 0, stream>>>(scan_part, gold_part, (float*)d_out);
    } else if (ws_size >= xh_bytes + 2048) {
        float* xs        = (float*)d_ws;
        float* scan_part = (float*)((char*)d_ws + xh_bytes);
        float* gold_part = scan_part + 256;
        crf_xs32_kernel<<<16384, 256, 0, stream>>>(emit, xs);
        crf_scan_mx_kernel<<<16, 64, 0, stream>>>(emit, xs, Tm, scan_part);
        crf_gold_kernel<<<256, 256, 0, stream>>>(emit, Tm, labels, startp, gold_part);
        crf_final_kernel<<<1, 256, 0, stream>>>(scan_part, gold_part, (float*)d_out);
    } else {
        float* scan_part = (float*)d_ws;
        float* gold_part = scan_part + 256;
        crf_scan_bf16_kernel<<<16, 64, 0, stream>>>(emit, Tm, scan_part);
        crf_gold_kernel<<<256, 256, 0, stream>>>(emit, Tm, labels, startp, gold_part);
        crf_final_kernel<<<1, 256, 0, stream>>>(scan_part, gold_part, (float*)d_out);
    }
}

// Round 12
// 212.891 us; speedup vs baseline: 1.8003x; 1.8003x over previous
//
#include <hip/hip_runtime.h>

// CRF loss, S=512, B=256, L=128; out = sum_b log_z_b - gold.
//
// R12 fast scan: producer/consumer wave specialization. 16 blocks x 128 thr.
//   wave0 (consumer): 511-step recurrence, 8x mfma_scale_f32_16x16x128_f8f6f4
//     per step, xh read ONLY from LDS (ds_read_b128). No global loads in the
//     loop => no vmcnt drain in the chain (R10's dual-chain experiment proved
//     the per-step ~550cyc stall is a drain-all vmcnt wait: two independent
//     chains gave ZERO overlap, 829 vs 830 cyc/step).
//   wave1 (producer): stages next 4 timesteps (4x8KB) into the other LDS half
//     via global_load_lds(16B); its vmcnt(0)-before-barrier drain (~600cyc)
//     hides under the consumer's ~1200cyc per buffer.
// LDS: 2 halves x 4 steps x 8KB = 64KB, XOR-swizzled via PRE-SWIZZLED GLOBAL
// SOURCE (guide m173/T2; global_load_lds dest must stay linear, m104):
//   involution: LDS slot s holds global chunk s ^ ((s>>5)&7)  (16B chunks)
//   consumer reads slot 32b + ((4jt+g) ^ (b&7)) -> conflict-free b128.
//
// Per-step scale: R9's PROVEN direct normalization (absmax 0.0): sb byte =
// 250 - exp_field(shfl(ac00, b)), applied via MFMA B-scale (e8m0) next step;
// L += 127-sb exactly; Sum_t X_t added in final kernel (coalesced). State
// e5m2, A=exp(T)^T permuted e4m3. Layouts verified R5-R9.
//
// Fallbacks: [ws >= xh+X: fast] [ws >= xs: R8 exact-max, proven] [else bf16].

#define LOG2E 1.4426950408889634f
#define LN2F  0.6931471805599453f

typedef float        f32x4  __attribute__((ext_vector_type(4)));
typedef int          i32x8  __attribute__((ext_vector_type(8)));
typedef unsigned int u32x4  __attribute__((ext_vector_type(4)));
typedef short        bf16x8 __attribute__((ext_vector_type(8)));
typedef __bf16       bf16x2 __attribute__((ext_vector_type(2)));

__device__ __forceinline__ unsigned packbf2(float lo, float hi) {
    bf16x2 p = { (__bf16)lo, (__bf16)hi };
    return __builtin_bit_cast(unsigned, p);
}

#define MFMAX(Aop, Bop, SCL) \
    __builtin_amdgcn_mfma_scale_f32_16x16x128_f8f6f4( \
        Aop, Bop, zero4, 0, 1, 0, 0x7F7F7F7F, 0, SCL)

// ================= xs prenormalize kernel =================
// Row r = t*256+b: xh = exp(emit)*2^-X, row max in [1,2); X[r] int32.
__global__ __launch_bounds__(256) void crf_xsn_kernel(
    const float* __restrict__ emit, float* __restrict__ xh,
    int* __restrict__ X)
{
    const int tid = threadIdx.x;
    const int r   = blockIdx.x * 16 + (tid >> 4);
    const int s   = tid & 15;
    const float4* src = (const float4*)emit + (size_t)r * 32 + s * 2;
    float4 e0 = src[0], e1 = src[1];
    float x0 = __builtin_amdgcn_exp2f(e0.x * LOG2E);
    float x1 = __builtin_amdgcn_exp2f(e0.y * LOG2E);
    float x2 = __builtin_amdgcn_exp2f(e0.z * LOG2E);
    float x3 = __builtin_amdgcn_exp2f(e0.w * LOG2E);
    float x4 = __builtin_amdgcn_exp2f(e1.x * LOG2E);
    float x5 = __builtin_amdgcn_exp2f(e1.y * LOG2E);
    float x6 = __builtin_amdgcn_exp2f(e1.z * LOG2E);
    float x7 = __builtin_amdgcn_exp2f(e1.w * LOG2E);
    float m = fmaxf(fmaxf(fmaxf(x0, x1), fmaxf(x2, x3)),
                    fmaxf(fmaxf(x4, x5), fmaxf(x6, x7)));
#pragma unroll
    for (int off = 1; off < 16; off <<= 1)
        m = fmaxf(m, __shfl_xor(m, off));
    const int eb = (__float_as_int(m) >> 23) & 0xFF;
    const float scl = __int_as_float((254 - eb) << 23);
    float4 o0, o1;
    o0.x = x0 * scl; o0.y = x1 * scl; o0.z = x2 * scl; o0.w = x3 * scl;
    o1.x = x4 * scl; o1.y = x5 * scl; o1.z = x6 * scl; o1.w = x7 * scl;
    float4* dst = (float4*)xh + (size_t)r * 32 + s * 2;
    dst[0] = o0; dst[1] = o1;
    if (s == 0) X[r] = eb - 127;
}

// ================= R12 producer/consumer fast scan =================
// Producer: stage buffer K (t = 1+4K .. 4+4K) into LDS half K&1.
// Pre-swizzled source: LDS slot s gets global chunk s ^ ((s>>5)&7).
#define STAGE(K) do {                                                         \
    const int tb_ = 1 + 4 * (K);                                              \
    _Pragma("unroll") for (int tt_ = 0; tt_ < 4; ++tt_) {                     \
        int t_ = tb_ + tt_; if (t_ > 511) t_ = 511;                           \
        const float* sb_ = xh + (size_t)t_ * 32768 + gb * 2048;               \
        _Pragma("unroll") for (int i_ = 0; i_ < 8; ++i_) {                    \
            const int s_  = 64 * i_ + pn;                                     \
            const int ch_ = s_ ^ ((s_ >> 5) & 7);                             \
            __builtin_amdgcn_global_load_lds(                                 \
                (const void*)(sb_ + 4 * ch_),                                 \
                (void*)&sbuf[(K) & 1][tt_][i_ * 256], 16, 0, 0);              \
        }                                                                     \
    }                                                                         \
} while (0)

// Consumer: one scan step from LDS half HALF, sub-step TT.
#define STEPL(HALF, TT, LAST) do {                                            \
    f32x4 xv[8];                                                              \
    _Pragma("unroll") for (int jt = 0; jt < 8; ++jt) {                        \
        const int sl = 32 * b + ((4 * jt + g) ^ bsw);                         \
        xv[jt] = *(const f32x4*)&sbuf[HALF][TT][sl * 4];                      \
    }                                                                         \
    f32x4 ac[8];                                                              \
    _Pragma("unroll") for (int jt = 0; jt < 8; ++jt)                          \
        ac[jt] = MFMAX(Afr[jt], Bq, sclw);                                    \
    float a00 = __shfl(ac[0][0], b);                                          \
    int ea  = (__float_as_int(a00) >> 23) & 0xFF;                             \
    int sb2 = 250 - ea;                                                       \
    sb2 = sb2 < 1 ? 1 : (sb2 > 254 ? 254 : sb2);                              \
    f32x4 vv[8];                                                              \
    _Pragma("unroll") for (int jt = 0; jt < 8; ++jt)                          \
        vv[jt] = ac[jt] * xv[jt];                                             \
    if (LAST) {                                                               \
        fin = 0.f;                                                            \
        _Pragma("unroll") for (int jt = 0; jt < 8; ++jt)                      \
            fin += (vv[jt][0] + vv[jt][1]) + (vv[jt][2] + vv[jt][3]);         \
    } else {                                                                  \
        L += 127 - sb2;                                                       \
        sclw = sb2 * 0x01010101;                                              \
        _Pragma("unroll") for (int d = 0; d < 8; ++d) {                       \
            int bw = __builtin_amdgcn_cvt_pk_bf8_f32(vv[d][0], vv[d][1], 0, false); \
            Bq[d]  = __builtin_amdgcn_cvt_pk_bf8_f32(vv[d][2], vv[d][3], bw, true); \
        }                                                                     \
    }                                                                         \
} while (0)

__global__ __launch_bounds__(128, 1) void crf_scan_pc_kernel(
    const float* __restrict__ xh,
    const float* __restrict__ Tm,
    float* __restrict__ scan2)   // (256) log2-domain partial (no Sum_X)
{
    const int gb  = blockIdx.x;      // batch group 0..15
    const int tid = threadIdx.x;     // 0..127
    const int pw  = tid >> 6;        // 0 = consumer wave, 1 = producer wave
    const int pn  = tid & 63;        // lane in wave
    const int l   = pn;
    const int b   = l & 15;
    const int g   = l >> 4;
    const int bsw = b & 7;
    const int bg  = gb * 16 + b;
    const int lb  = 32 * bg + g;

    __shared__ __align__(16) float sbuf[2][4][2048];   // 64 KiB

    const f32x4* xhf = (const f32x4*)xh;
    const f32x4 zero4 = {0.f, 0.f, 0.f, 0.f};

    // Producer: kick off buffer 0 immediately.
    if (pw) STAGE(0);

    // ---- constant A (e4m3): Afr[jt] dword d byte c =
    // A[16jt+b][k~=32g+4d+c] = exp(T[16d+4g+c][16jt+b]) ----
    i32x8 Afr[8];
#pragma unroll
    for (int jt = 0; jt < 8; ++jt)
#pragma unroll
        for (int d = 0; d < 8; ++d) {
            const int col = 16 * jt + b;
            const int rb  = 16 * d + 4 * g;
            float a0 = __builtin_amdgcn_exp2f(Tm[(rb + 0) * 128 + col] * LOG2E);
            float a1 = __builtin_amdgcn_exp2f(Tm[(rb + 1) * 128 + col] * LOG2E);
            float a2 = __builtin_amdgcn_exp2f(Tm[(rb + 2) * 128 + col] * LOG2E);
            float a3 = __builtin_amdgcn_exp2f(Tm[(rb + 3) * 128 + col] * LOG2E);
            int w = __builtin_amdgcn_cvt_pk_fp8_f32(a0, a1, 0, false);
            Afr[jt][d] = __builtin_amdgcn_cvt_pk_fp8_f32(a2, a3, w, true);
        }

    // ---- t=0 init (consumer data; computed by both waves, harmless) ----
    i32x8 Bq;
    int   L    = 4;                      // accounts initial sclw=123 (2^-4)
    int   sclw = 123 * 0x01010101;
    float fin  = 0.f;
    {
        f32x4 x0[8];
#pragma unroll
        for (int jt = 0; jt < 8; ++jt) x0[jt] = xhf[lb + 4 * jt];
#pragma unroll
        for (int d = 0; d < 8; ++d) {
            int bw = __builtin_amdgcn_cvt_pk_bf8_f32(x0[d][0], x0[d][1], 0, false);
            Bq[d]  = __builtin_amdgcn_cvt_pk_bf8_f32(x0[d][2], x0[d][3], bw, true);
        }
    }

    __syncthreads();   // buffer 0 staged

    // ---- main: 127 iterations x 4 steps (t = 1..508), then 3-step tail ----
#pragma unroll 1
    for (int k = 0; k < 127; ++k) {
        if (pw) {
            STAGE(k + 1);
        } else {
            const int h = k & 1;
            STEPL(h, 0, 0);
            STEPL(h, 1, 0);
            STEPL(h, 2, 0);
            STEPL(h, 3, 0);
        }
        __syncthreads();
    }
    // buffer 127 (half 1): t = 509, 510, 511
    if (!pw) {
        STEPL(1, 0, 0);
        STEPL(1, 1, 0);
        STEPL(1, 2, 1);

        fin += __shfl_xor(fin, 16);
        fin += __shfl_xor(fin, 32);
        if (l < 16)
            scan2[gb * 16 + l] = (float)L + __log2f(fin);
    }
}

// ================= R8 exact-max scan (proven; middle fallback) ============
#define STEPM(SLOT, TPF, DOPF, LAST) do {                                     \
    f32x4 ac[8];                                                              \
    _Pragma("unroll") for (int jt = 0; jt < 8; ++jt)                          \
        ac[jt] = MFMAX(Afr[jt], Bq, sclw);                                    \
    float vv[8][4];                                                           \
    _Pragma("unroll") for (int jt = 0; jt < 8; ++jt) {                        \
        f32x4 xw = xf[SLOT][jt];                                              \
        vv[jt][0] = ac[jt][0] * xw[0];                                        \
        vv[jt][1] = ac[jt][1] * xw[1];                                        \
        vv[jt][2] = ac[jt][2] * xw[2];                                        \
        vv[jt][3] = ac[jt][3] * xw[3];                                        \
    }                                                                         \
    if (DOPF) {                                                               \
        int tp = (TPF); if (tp > 511) tp = 511;                               \
        _Pragma("unroll") for (int jt = 0; jt < 8; ++jt)                      \
            xf[SLOT][jt] = xsf[8192 * tp + lb + 4 * jt];                      \
    }                                                                         \
    if (LAST) {                                                               \
        fin = 0.f;                                                            \
        _Pragma("unroll") for (int jt = 0; jt < 8; ++jt)                      \
            fin += (vv[jt][0] + vv[jt][1]) + (vv[jt][2] + vv[jt][3]);         \
    } else {                                                                  \
        float m8[8];                                                          \
        _Pragma("unroll") for (int jt = 0; jt < 8; ++jt)                      \
            m8[jt] = fmaxf(fmaxf(vv[jt][0], vv[jt][1]),                       \
                           fmaxf(vv[jt][2], vv[jt][3]));                      \
        float mx = fmaxf(fmaxf(fmaxf(m8[0], m8[1]), fmaxf(m8[2], m8[3])),     \
                         fmaxf(fmaxf(m8[4], m8[5]), fmaxf(m8[6], m8[7])));    \
        mx = fmaxf(mx, __shfl_xor(mx, 16));                                   \
        mx = fmaxf(mx, __shfl_xor(mx, 32));                                   \
        int Ee = (__float_as_int(mx) >> 23) & 0xFF;                           \
        if (Ee < 16)  Ee = 16;                                                \
        if (Ee > 250) Ee = 250;                                               \
        ls2 += Ee - 125;                                                      \
        sclw = (252 - Ee) * 0x01010101;                                       \
        _Pragma("unroll") for (int d = 0; d < 8; ++d) {                       \
            int bw = __builtin_amdgcn_cvt_pk_bf8_f32(vv[d][0], vv[d][1], 0, false); \
            Bq[d]  = __builtin_amdgcn_cvt_pk_bf8_f32(vv[d][2], vv[d][3], bw, true); \
        }                                                                     \
    }                                                                         \
} while (0)

__global__ __launch_bounds__(256) void crf_xs32_kernel(
    const float* __restrict__ emit, float* __restrict__ xs)
{
    const size_t i = (size_t)blockIdx.x * 256 + threadIdx.x;
    const float4 e = ((const float4*)emit)[i];
    float4 o;
    o.x = __builtin_amdgcn_exp2f(e.x * LOG2E);
    o.y = __builtin_amdgcn_exp2f(e.y * LOG2E);
    o.z = __builtin_amdgcn_exp2f(e.z * LOG2E);
    o.w = __builtin_amdgcn_exp2f(e.w * LOG2E);
    ((float4*)xs)[i] = o;
}

__global__ __launch_bounds__(64, 1) void crf_scan_mx_kernel(
    const float* __restrict__ emit,
    const float* __restrict__ xs,
    const float* __restrict__ Tm,
    float* __restrict__ scan_part)
{
    const int gb = blockIdx.x;
    const int l  = threadIdx.x;
    const int b  = l & 15;
    const int g  = l >> 4;
    const int bg = gb * 16 + b;
    const int lb = 32 * bg + g;

    const f32x4* xsf = (const f32x4*)xs;
    const f32x4 zero4 = {0.f, 0.f, 0.f, 0.f};

    i32x8 Afr[8];
#pragma unroll
    for (int jt = 0; jt < 8; ++jt)
#pragma unroll
        for (int d = 0; d < 8; ++d) {
            const int col = 16 * jt + b;
            const int rb  = 16 * d + 4 * g;
            float a0 = __builtin_amdgcn_exp2f(Tm[(rb + 0) * 128 + col] * LOG2E);
            float a1 = __builtin_amdgcn_exp2f(Tm[(rb + 1) * 128 + col] * LOG2E);
            float a2 = __builtin_amdgcn_exp2f(Tm[(rb + 2) * 128 + col] * LOG2E);
            float a3 = __builtin_amdgcn_exp2f(Tm[(rb + 3) * 128 + col] * LOG2E);
            int w = __builtin_amdgcn_cvt_pk_fp8_f32(a0, a1, 0, false);
            Afr[jt][d] = __builtin_amdgcn_cvt_pk_fp8_f32(a2, a3, w, true);
        }

    i32x8 Bq;
    int ls2 = 0;
    int sclw;
    {
        float x0[8][4];
#pragma unroll
        for (int jt = 0; jt < 8; ++jt) {
            float4 e = ((const float4*)emit)[lb + 4 * jt];
            x0[jt][0] = __builtin_amdgcn_exp2f(e.x * LOG2E);
            x0[jt][1] = __builtin_amdgcn_exp2f(e.y * LOG2E);
            x0[jt][2] = __builtin_amdgcn_exp2f(e.z * LOG2E);
            x0[jt][3] = __builtin_amdgcn_exp2f(e.w * LOG2E);
        }
        float m8[8];
#pragma unroll
        for (int jt = 0; jt < 8; ++jt)
            m8[jt] = fmaxf(fmaxf(x0[jt][0], x0[jt][1]),
                           fmaxf(x0[jt][2], x0[jt][3]));
        float mx = fmaxf(fmaxf(fmaxf(m8[0], m8[1]), fmaxf(m8[2], m8[3])),
                         fmaxf(fmaxf(m8[4], m8[5]), fmaxf(m8[6], m8[7])));
        mx = fmaxf(mx, __shfl_xor(mx, 16));
        mx = fmaxf(mx, __shfl_xor(mx, 32));
        int Ee = (__float_as_int(mx) >> 23) & 0xFF;
        if (Ee < 16)  Ee = 16;
        if (Ee > 250) Ee = 250;
        ls2 += Ee - 125;
        sclw = (252 - Ee) * 0x01010101;
#pragma unroll
        for (int d = 0; d < 8; ++d) {
            int bw = __builtin_amdgcn_cvt_pk_bf8_f32(x0[d][0], x0[d][1], 0, false);
            Bq[d]  = __builtin_amdgcn_cvt_pk_bf8_f32(x0[d][2], x0[d][3], bw, true);
        }
    }

    f32x4 xf[4][8];
#pragma unroll
    for (int k = 0; k < 4; ++k)
#pragma unroll
        for (int jt = 0; jt < 8; ++jt)
            xf[k][jt] = xsf[8192 * (1 + k) + lb + 4 * jt];

    float fin = 0.f;

#pragma unroll 1
    for (int grp = 0; grp < 127; ++grp) {
        const int t0 = 1 + 4 * grp;
        STEPM(0, t0 + 4, 1, 0);
        STEPM(1, t0 + 5, 1, 0);
        STEPM(2, t0 + 6, 1, 0);
        STEPM(3, t0 + 7, 1, 0);
    }
    STEPM(0, 0, 0, 0);
    STEPM(1, 0, 0, 0);
    STEPM(2, 0, 0, 1);

    fin += __shfl_xor(fin, 16);
    fin += __shfl_xor(fin, 32);
    if (l < 16)
        scan_part[gb * 16 + l] = ((float)ls2 + __log2f(fin)) * LN2F;
}

// ================= bf16 fallback scan =================
#define MFMAB(Aop, Bop, Cop) \
    __builtin_amdgcn_mfma_f32_16x16x32_bf16( \
        __builtin_bit_cast(bf16x8, Aop), __builtin_bit_cast(bf16x8, Bop), Cop, 0, 0, 0)

#define STEPB(SLOT, TPF, DOPF, RN, LAST) do {                                 \
    f32x4 ac[8];                                                              \
    _Pragma("unroll") for (int jt = 0; jt < 8; ++jt)                          \
        ac[jt] = MFMAB(Afr[0][jt], Bf[0], zero4);                             \
    _Pragma("unroll") for (int ch = 1; ch < 4; ++ch)                          \
        _Pragma("unroll") for (int jt = 0; jt < 8; ++jt)                      \
            ac[jt] = MFMAB(Afr[ch][jt], Bf[ch], ac[jt]);                      \
    float xv[8][4];                                                           \
    _Pragma("unroll") for (int jt = 0; jt < 8; ++jt) {                        \
        float4 xw = xbf[SLOT][jt];                                            \
        xv[jt][0] = __builtin_amdgcn_exp2f(xw.x * LOG2E);                     \
        xv[jt][1] = __builtin_amdgcn_exp2f(xw.y * LOG2E);                     \
        xv[jt][2] = __builtin_amdgcn_exp2f(xw.z * LOG2E);                     \
        xv[jt][3] = __builtin_amdgcn_exp2f(xw.w * LOG2E);                     \
    }                                                                         \
    if (DOPF) {                                                               \
        int tp = (TPF); if (tp > 511) tp = 511;                               \
        _Pragma("unroll") for (int jt = 0; jt < 8; ++jt)                      \
            xbf[SLOT][jt] = emf4[8192 * tp + lb + 4 * jt];                    \
    }                                                                         \
    float vv[8][4];                                                           \
    _Pragma("unroll") for (int jt = 0; jt < 8; ++jt)                          \
        _Pragma("unroll") for (int r = 0; r < 4; ++r)                         \
            vv[jt][r] = ac[jt][r] * xv[jt][r];                                \
    if (RN) {                                                                 \
        float mx = vv[0][0];                                                  \
        _Pragma("unroll") for (int jt = 0; jt < 8; ++jt)                      \
            _Pragma("unroll") for (int r = 0; r < 4; ++r)                     \
                mx = fmaxf(mx, vv[jt][r]);                                    \
        mx = fmaxf(mx, __shfl_xor(mx, 16));                                   \
        mx = fmaxf(mx, __shfl_xor(mx, 32));                                   \
        int Ee = (__float_as_int(mx) >> 23) & 0xFF;                           \
        if (Ee > 254) Ee = 254;                                               \
        ls2 += Ee - 127;                                                      \
        float scl = __int_as_float((254 - Ee) << 23);                         \
        _Pragma("unroll") for (int jt = 0; jt < 8; ++jt)                      \
            _Pragma("unroll") for (int r = 0; r < 4; ++r)                     \
                vv[jt][r] *= scl;                                             \
    }                                                                         \
    if (LAST) {                                                               \
        fin = 0.f;                                                            \
        _Pragma("unroll") for (int jt = 0; jt < 8; ++jt)                      \
            fin += (vv[jt][0] + vv[jt][1]) + (vv[jt][2] + vv[jt][3]);         \
    } else {                                                                  \
        _Pragma("unroll") for (int ch = 0; ch < 4; ++ch) {                    \
            Bf[ch][0] = packbf2(vv[2*ch][0],     vv[2*ch][1]);                \
            Bf[ch][1] = packbf2(vv[2*ch][2],     vv[2*ch][3]);                \
            Bf[ch][2] = packbf2(vv[2*ch + 1][0], vv[2*ch + 1][1]);            \
            Bf[ch][3] = packbf2(vv[2*ch + 1][2], vv[2*ch + 1][3]);            \
        }                                                                     \
    }                                                                         \
} while (0)

__global__ __launch_bounds__(64, 1) void crf_scan_bf16_kernel(
    const float* __restrict__ emit,
    const float* __restrict__ Tm,
    float* __restrict__ scan_part)
{
    const int gb = blockIdx.x;
    const int l  = threadIdx.x;
    const int b  = l & 15;
    const int g  = l >> 4;
    const int bg = gb * 16 + b;
    const int lb = 32 * bg + g;

    const float4* emf4 = (const float4*)emit;
    const f32x4 zero4 = {0.f, 0.f, 0.f, 0.f};

    u32x4 Afr[4][8];
#pragma unroll
    for (int ch = 0; ch < 4; ++ch)
#pragma unroll
        for (int p = 0; p < 4; ++p) {
            const int e0 = 2 * p, e1 = 2 * p + 1;
            const int jp0 = 32 * ch + 16 * (e0 >> 2) + 4 * g + (e0 & 3);
            const int jp1 = 32 * ch + 16 * (e1 >> 2) + 4 * g + (e1 & 3);
#pragma unroll
            for (int jt = 0; jt < 8; ++jt) {
                float a0 = __builtin_amdgcn_exp2f(Tm[jp0 * 128 + 16 * jt + b] * LOG2E);
                float a1 = __builtin_amdgcn_exp2f(Tm[jp1 * 128 + 16 * jt + b] * LOG2E);
                Afr[ch][jt][p] = packbf2(a0, a1);
            }
        }

    u32x4 Bf[4];
    {
        float x0[8][4];
#pragma unroll
        for (int jt = 0; jt < 8; ++jt) {
            float4 e = emf4[lb + 4 * jt];
            x0[jt][0] = __builtin_amdgcn_exp2f(e.x * LOG2E);
            x0[jt][1] = __builtin_amdgcn_exp2f(e.y * LOG2E);
            x0[jt][2] = __builtin_amdgcn_exp2f(e.z * LOG2E);
            x0[jt][3] = __builtin_amdgcn_exp2f(e.w * LOG2E);
        }
#pragma unroll
        for (int ch = 0; ch < 4; ++ch) {
            Bf[ch][0] = packbf2(x0[2 * ch][0],     x0[2 * ch][1]);
            Bf[ch][1] = packbf2(x0[2 * ch][2],     x0[2 * ch][3]);
            Bf[ch][2] = packbf2(x0[2 * ch + 1][0], x0[2 * ch + 1][1]);
            Bf[ch][3] = packbf2(x0[2 * ch + 1][2], x0[2 * ch + 1][3]);
        }
    }

    float4 xbf[4][8];
#pragma unroll
    for (int k = 0; k < 4; ++k)
#pragma unroll
        for (int jt = 0; jt < 8; ++jt)
            xbf[k][jt] = emf4[8192 * (1 + k) + lb + 4 * jt];

    int ls2 = 0;
    float fin = 0.f;

#pragma unroll 1
    for (int grp = 0; grp < 63; ++grp) {
        const int t0 = 1 + 8 * grp;
        STEPB(0, t0 + 4,  1, 0, 0);
        STEPB(1, t0 + 5,  1, 0, 0);
        STEPB(2, t0 + 6,  1, 0, 0);
        STEPB(3, t0 + 7,  1, 0, 0);
        STEPB(0, t0 + 8,  1, 0, 0);
        STEPB(1, t0 + 9,  1, 0, 0);
        STEPB(2, t0 + 10, 1, 0, 0);
        STEPB(3, t0 + 11, 1, 1, 0);
    }
    STEPB(0, 509, 1, 0, 0);
    STEPB(1, 510, 1, 0, 0);
    STEPB(2, 511, 1, 0, 0);
    STEPB(3, 0,   0, 0, 0);
    STEPB(0, 0,   0, 0, 0);
    STEPB(1, 0,   0, 0, 0);
    STEPB(2, 0,   0, 0, 1);

    fin += __shfl_xor(fin, 16);
    fin += __shfl_xor(fin, 32);
    if (l < 16)
        scan_part[gb * 16 + l] = ((float)ls2 + __log2f(fin)) * LN2F;
}

// ================= gold + final =================
__global__ __launch_bounds__(256) void crf_gold_kernel(
    const float* __restrict__ emit, const float* __restrict__ Tm,
    const int* __restrict__ labels, const int* __restrict__ startp,
    float* __restrict__ gold_part)
{
    const int b = blockIdx.x, tid = threadIdx.x;
    __shared__ int lab[512];
    __shared__ float r[4];
    lab[tid]       = labels[b * 512 + tid];
    lab[tid + 256] = labels[b * 512 + tid + 256];
    __syncthreads();
    float s = 0.f;
    {
        int y0 = lab[tid];
        int p0 = (tid == 0) ? startp[0] : lab[tid - 1];
        s += emit[((size_t)tid * 256 + b) * 128 + y0] + Tm[p0 * 128 + y0];
        int t1 = tid + 256;
        int y1 = lab[t1];
        int p1 = lab[t1 - 1];
        s += emit[((size_t)t1 * 256 + b) * 128 + y1] + Tm[p1 * 128 + y1];
    }
#pragma unroll
    for (int off = 1; off < 64; off <<= 1) s += __shfl_xor(s, off);
    if ((tid & 63) == 0) r[tid >> 6] = s;
    __syncthreads();
    if (tid == 0) gold_part[b] = (r[0] + r[1]) + (r[2] + r[3]);
}

// fast path: adds Sum_t X[t*256+b] (coalesced) to scan2, converts to nats.
__global__ __launch_bounds__(256) void crf_final2_kernel(
    const float* __restrict__ scan2, const int* __restrict__ X,
    const float* __restrict__ gold_part, float* __restrict__ out)
{
    const int tid = threadIdx.x;
    int sx = 0;
#pragma unroll 8
    for (int t = 0; t < 512; ++t) sx += X[t * 256 + tid];
    __shared__ float r[4];
    float v = (scan2[tid] + (float)sx) * LN2F - gold_part[tid];
#pragma unroll
    for (int off = 1; off < 64; off <<= 1) v += __shfl_xor(v, off);
    if ((tid & 63) == 0) r[tid >> 6] = v;
    __syncthreads();
    if (tid == 0) out[0] = (r[0] + r[1]) + (r[2] + r[3]);
}

__global__ __launch_bounds__(256) void crf_final_kernel(
    const float* __restrict__ scan_part, const float* __restrict__ gold_part,
    float* __restrict__ out)
{
    const int tid = threadIdx.x;
    __shared__ float r[4];
    float v = scan_part[tid] - gold_part[tid];
#pragma unroll
    for (int off = 1; off < 64; off <<= 1) v += __shfl_xor(v, off);
    if ((tid & 63) == 0) r[tid >> 6] = v;
    __syncthreads();
    if (tid == 0) out[0] = (r[0] + r[1]) + (r[2] + r[3]);
}

extern "C" void kernel_launch(void* const* d_in, const int* in_sizes, int n_in,
                              void* d_out, int out_size, void* d_ws, size_t ws_size,
                              hipStream_t stream) {
    const float* emit   = (const float*)d_in[0];
    const float* Tm     = (const float*)d_in[1];
    const int*   labels = (const int*)d_in[2];
    const int*   startp = (const int*)d_in[3];

    const size_t xh_bytes = (size_t)512 * 256 * 128 * 4;   // 67,108,864
    const size_t X_bytes  = (size_t)512 * 256 * 4;         // 524,288

    if (ws_size >= xh_bytes + X_bytes + 4096) {
        float* xh        = (float*)d_ws;
        int*   X         = (int*)((char*)d_ws + xh_bytes);
        float* scan2     = (float*)((char*)d_ws + xh_bytes + X_bytes);
        float* gold_part = scan2 + 256;
        crf_xsn_kernel<<<8192, 256, 0, stream>>>(emit, xh, X);
        crf_scan_pc_kernel<<<16, 128, 0, stream>>>(xh, Tm, scan2);
        crf_gold_kernel<<<256, 256, 0, stream>>>(emit, Tm, labels, startp, gold_part);
        crf_final2_kernel<<<1, 256, 0, stream>>>(scan2, X, gold_part, (float*)d_out);
    } else if (ws_size >= xh_bytes + 4096) {
        float* xs        = (float*)d_ws;
        float* scan_part = (float*)((char*)d_ws + xh_bytes);
        float* gold_part = scan_part + 256;
        crf_xs32_kernel<<<16384, 256, 0, stream>>>(emit, xs);
        crf_scan_mx_kernel<<<16, 64, 0, stream>>>(emit, xs, Tm, scan_part);
        crf_gold_kernel<<<256, 256, 0, stream>>>(emit, Tm, labels, startp, gold_part);
        crf_final_kernel<<<1, 256, 0, stream>>>(scan_part, gold_part, (float*)d_out);
    } else {
        float* scan_part = (float*)d_ws;
        float* gold_part = scan_part + 256;
        crf_scan_bf16_kernel<<<16, 64, 0, stream>>>(emit, Tm, scan_part);
        crf_gold_kernel<<<256, 256, 0, stream>>>(emit, Tm, labels, startp, gold_part);
        crf_final_kernel<<<1, 256, 0, stream>>>(scan_part, gold_part, (float*)d_out);
    }
}

// Round 13
// 74.331 us; speedup vs baseline: 5.1562x; 2.8641x over previous
//
#include <hip/hip_runtime.h>

// CRF loss, S=512, B=256, L=128; out = sum_b log_z_b - gold.
//
// R13: ASSOCIATIVE CHUNKED SCAN. The 511-step recurrence v <- v*M_t
// (M_t[i,j] = E[i,j]*x_t[j], E = exp(T)) is a product of positive matrices;
// Hilbert-metric contraction per multiply is tanh(Delta(E)/4) ~ 0.39
// (E entries in [0.66,1.52]), so a 16-step chunk product P_i is rank-1 to
// ~0.39^14 ~ 4e-6:   P_i ~ x_i y_i^T / (1^T x_i),
//   y_i^T = 1^T P_i  (forward chain from ones  — the PROVEN R9/R12 step),
//   x_i   = P_i 1    (backward chain from ones — same MFMA machinery,
//                     A = E^pi instead of E^T^pi, x-mul on input).
// Error budget: threshold 1.4e4 on ~7e5 output => ~54 nats/batch; rank-1
// error ~1e-6 nats/chunk. 32 chunks x 2 dirs x 16 groups = 1024 independent
// waves => critical path drops 511 -> 16 steps.
//
// Chunk chains: 8x mfma_scale_f32_16x16x128_f8f6f4 per step, state bf8 in
// registers, per-step power-of-2 scale sb = (250|248) - e(shfl(ac00,b))
// applied via the MFMA B-scale (e8m0), per-column L accounting exact
// (L += 127-sb). No x-prenorm: ranges re-proven (x <= 2^7.9 worst entry):
//   fwd: ac in [2^-4.6, 2^4], vv <= 2^12   << e5m2 max 2^15.8
//   bwd: extra margin sb = 248-ea; w = x.u <= 2^12.6; cvt saturates safely.
// Combine (per batch, 32 sequential rank-1 applies): v <- (v.x_i)/(1^T x_i)
// * y_i, power-of-2 renorm, Lv += Ly_i (x's scale cancels in the ratio).
//
// Layouts (verified R5-R12, absmax 0.0): B byte e=4d+c of dword d holds
// k~=32g+4d+c; D tile d reg r (j=16d+4g+r) at byte 4d+r;
// fwd A[jt][d] byte c = exp(T[16d+4g+c][16jt+b]); bwd swaps the indices.
//
// ws: yx[2][32][256][128] f32 (8.4MB) + Ls[2][32][256] + parts (~8.6MB).
// Fallback (ws < 9MB): R7-proven bf16 in-register full scan.

#define LOG2E 1.4426950408889634f
#define LN2F  0.6931471805599453f

typedef float        f32x4  __attribute__((ext_vector_type(4)));
typedef int          i32x8  __attribute__((ext_vector_type(8)));
typedef unsigned int u32x4  __attribute__((ext_vector_type(4)));
typedef short        bf16x8 __attribute__((ext_vector_type(8)));
typedef __bf16       bf16x2 __attribute__((ext_vector_type(2)));

__device__ __forceinline__ unsigned packbf2(float lo, float hi) {
    bf16x2 p = { (__bf16)lo, (__bf16)hi };
    return __builtin_bit_cast(unsigned, p);
}

#define MFMAX(Aop, Bop, SCL) \
    __builtin_amdgcn_mfma_scale_f32_16x16x128_f8f6f4( \
        Aop, Bop, zero4, 0, 1, 0, 0x7F7F7F7F, 0, SCL)

// ================= chunk kernel: 1024 blocks x 64 thr =================
// blockIdx: dir = bi>>9 (0 fwd/y, 1 bwd/x), chunk = (bi>>4)&31, gb = bi&15.
__global__ __launch_bounds__(64, 1) void crf_chunk_kernel(
    const float* __restrict__ emit,   // (512,256,128)
    const float* __restrict__ Tm,     // (128,128)
    float* __restrict__ yx,           // [2][32][256][128]
    int*   __restrict__ Ls)           // [2][32][256]
{
    const int bi    = blockIdx.x;
    const int dir   = bi >> 9;
    const int chunk = (bi >> 4) & 31;
    const int gb    = bi & 15;
    const int l     = threadIdx.x;
    const int b     = l & 15;
    const int g     = l >> 4;
    const int bg    = gb * 16 + b;
    const int lb    = 32 * bg + g;            // f32x4 index within a t-row
    const int NT    = (chunk == 31) ? 15 : 16;
    const int t0    = 1 + 16 * chunk;

    const f32x4* emf = (const f32x4*)emit;
    const f32x4 zero4 = {0.f, 0.f, 0.f, 0.f};

#define TK(K) (dir ? (t0 + NT - 1 - (K)) : (t0 + (K)))

    // ---- A fragments (e4m3) ----
    i32x8 Afr[8];
#pragma unroll
    for (int jt = 0; jt < 8; ++jt)
#pragma unroll
        for (int d = 0; d < 8; ++d) {
            float a0, a1, a2, a3;
            if (!dir) {   // fwd: A[j][k~] = E[16d+4g+c][16jt+b]
                const int rb = 16 * d + 4 * g, col = 16 * jt + b;
                a0 = __builtin_amdgcn_exp2f(Tm[(rb + 0) * 128 + col] * LOG2E);
                a1 = __builtin_amdgcn_exp2f(Tm[(rb + 1) * 128 + col] * LOG2E);
                a2 = __builtin_amdgcn_exp2f(Tm[(rb + 2) * 128 + col] * LOG2E);
                a3 = __builtin_amdgcn_exp2f(Tm[(rb + 3) * 128 + col] * LOG2E);
            } else {      // bwd: A2[i][k~] = E[16jt+b][16d+4g+c]
                const int row = 16 * jt + b, cb = 16 * d + 4 * g;
                a0 = __builtin_amdgcn_exp2f(Tm[row * 128 + cb + 0] * LOG2E);
                a1 = __builtin_amdgcn_exp2f(Tm[row * 128 + cb + 1] * LOG2E);
                a2 = __builtin_amdgcn_exp2f(Tm[row * 128 + cb + 2] * LOG2E);
                a3 = __builtin_amdgcn_exp2f(Tm[row * 128 + cb + 3] * LOG2E);
            }
            int w = __builtin_amdgcn_cvt_pk_fp8_f32(a0, a1, 0, false);
            Afr[jt][d] = __builtin_amdgcn_cvt_pk_fp8_f32(a2, a3, w, true);
        }

    // ---- init state ----
    i32x8 Bq;
    f32x4 u[8];
    int L, sclw;
    if (!dir) {
        int one2 = __builtin_amdgcn_cvt_pk_bf8_f32(1.f, 1.f, 0, false);
        one2 = __builtin_amdgcn_cvt_pk_bf8_f32(1.f, 1.f, one2, true);
#pragma unroll
        for (int d = 0; d < 8; ++d) Bq[d] = one2;
        L = 4;  sclw = 123 * 0x01010101;      // sigma = -4
    } else {
#pragma unroll
        for (int d = 0; d < 8; ++d) u[d] = (f32x4){1.f, 1.f, 1.f, 1.f};
        L = 8;  sclw = 119 * 0x01010101;      // sigma = -8 (extra margin)
    }

    // ---- prefetch first two timesteps ----
    f32x4 xf[2][8];
#pragma unroll
    for (int jt = 0; jt < 8; ++jt) {
        xf[0][jt] = emf[(size_t)TK(0) * 8192 + lb + 4 * jt];
        xf[1][jt] = emf[(size_t)TK(1) * 8192 + lb + 4 * jt];
    }

    f32x4 outv[8];
#pragma unroll
    for (int k = 0; k < 16; ++k) {
        if (k < NT) {
            f32x4 xv[8];
#pragma unroll
            for (int jt = 0; jt < 8; ++jt) {
                f32x4 e = xf[k & 1][jt];
                xv[jt][0] = __builtin_amdgcn_exp2f(e[0] * LOG2E);
                xv[jt][1] = __builtin_amdgcn_exp2f(e[1] * LOG2E);
                xv[jt][2] = __builtin_amdgcn_exp2f(e[2] * LOG2E);
                xv[jt][3] = __builtin_amdgcn_exp2f(e[3] * LOG2E);
            }
            if (dir) {   // bwd: w = x .* u -> B operand
#pragma unroll
                for (int d = 0; d < 8; ++d) {
                    f32x4 w = xv[d] * u[d];
                    int bw = __builtin_amdgcn_cvt_pk_bf8_f32(w[0], w[1], 0, false);
                    Bq[d]  = __builtin_amdgcn_cvt_pk_bf8_f32(w[2], w[3], bw, true);
                }
            }
            f32x4 ac[8];
#pragma unroll
            for (int jt = 0; jt < 8; ++jt)
                ac[jt] = MFMAX(Afr[jt], Bq, sclw);
            float a00 = __shfl(ac[0][0], b);
            int ea = (__float_as_int(a00) >> 23) & 0xFF;
            int sb = (dir ? 248 : 250) - ea;
            sb = sb < 1 ? 1 : (sb > 254 ? 254 : sb);
            const bool last = (k == NT - 1);
            if (!last) { L += 127 - sb; sclw = sb * 0x01010101; }
            if (!dir) {
#pragma unroll
                for (int jt = 0; jt < 8; ++jt) {
                    f32x4 vv = ac[jt] * xv[jt];
                    if (last) outv[jt] = vv;
                    else {
                        int bw = __builtin_amdgcn_cvt_pk_bf8_f32(vv[0], vv[1], 0, false);
                        Bq[jt] = __builtin_amdgcn_cvt_pk_bf8_f32(vv[2], vv[3], bw, true);
                    }
                }
            } else {
#pragma unroll
                for (int jt = 0; jt < 8; ++jt) {
                    u[jt] = ac[jt];
                    if (last) outv[jt] = ac[jt];
                }
            }
            if (k + 2 < NT) {
#pragma unroll
                for (int jt = 0; jt < 8; ++jt)
                    xf[k & 1][jt] = emf[(size_t)TK(k + 2) * 8192 + lb + 4 * jt];
            }
        }
    }

    // ---- store chunk profile (f32) + per-column log2 scale ----
    const size_t base = ((size_t)(dir * 32 + chunk) * 256 + bg) * 128;
#pragma unroll
    for (int d = 0; d < 8; ++d)
        *(f32x4*)&yx[base + 16 * d + 4 * g] = outv[d];
    if (l < 16)
        Ls[(dir * 32 + chunk) * 256 + gb * 16 + l] = L;
#undef TK
}

// ================= combine: 256 blocks (one batch each) x 64 thr ========
__global__ __launch_bounds__(64) void crf_combine_kernel(
    const float* __restrict__ emit, const float* __restrict__ yx,
    const int* __restrict__ Ls, float* __restrict__ scan_part)
{
    const int b = blockIdx.x, l = threadIdx.x;
    float va = __builtin_amdgcn_exp2f(emit[b * 128 + l] * LOG2E);       // j=l
    float vb = __builtin_amdgcn_exp2f(emit[b * 128 + 64 + l] * LOG2E);  // j=l+64
    int Lv = 0;
#pragma unroll 1
    for (int i = 0; i < 32; ++i) {
        const float* xp = yx + ((size_t)(32 + i) * 256 + b) * 128;   // x_i (bwd)
        float xa = xp[l], xb = xp[64 + l];
        float sp = va * xa + vb * xb;
        float tp = xa + xb;
#pragma unroll
        for (int off = 1; off < 64; off <<= 1) {
            sp += __shfl_xor(sp, off);
            tp += __shfl_xor(tp, off);
        }
        float r = sp / tp;
        const float* yp = yx + ((size_t)i * 256 + b) * 128;          // y_i (fwd)
        va = r * yp[l];
        vb = r * yp[64 + l];
        Lv += Ls[i * 256 + b];                                       // Ly only
        float m = fmaxf(va, vb);
#pragma unroll
        for (int off = 1; off < 64; off <<= 1) m = fmaxf(m, __shfl_xor(m, off));
        int ef = (__float_as_int(m) >> 23) & 0xFF;
        float scl = __int_as_float((254 - ef) << 23);
        va *= scl; vb *= scl; Lv += ef - 127;
    }
    float s2 = va + vb;
#pragma unroll
    for (int off = 1; off < 64; off <<= 1) s2 += __shfl_xor(s2, off);
    if (l == 0)
        scan_part[b] = ((float)Lv + __log2f(s2)) * LN2F;
}

// ================= bf16 fallback full scan (R7, proven) =================
#define MFMAB(Aop, Bop, Cop) \
    __builtin_amdgcn_mfma_f32_16x16x32_bf16( \
        __builtin_bit_cast(bf16x8, Aop), __builtin_bit_cast(bf16x8, Bop), Cop, 0, 0, 0)

#define STEPB(SLOT, TPF, DOPF, RN, LAST) do {                                 \
    f32x4 ac[8];                                                              \
    _Pragma("unroll") for (int jt = 0; jt < 8; ++jt)                          \
        ac[jt] = MFMAB(Afr[0][jt], Bf[0], zero4);                             \
    _Pragma("unroll") for (int ch = 1; ch < 4; ++ch)                          \
        _Pragma("unroll") for (int jt = 0; jt < 8; ++jt)                      \
            ac[jt] = MFMAB(Afr[ch][jt], Bf[ch], ac[jt]);                      \
    float xv[8][4];                                                           \
    _Pragma("unroll") for (int jt = 0; jt < 8; ++jt) {                        \
        float4 xw = xbf[SLOT][jt];                                            \
        xv[jt][0] = __builtin_amdgcn_exp2f(xw.x * LOG2E);                     \
        xv[jt][1] = __builtin_amdgcn_exp2f(xw.y * LOG2E);                     \
        xv[jt][2] = __builtin_amdgcn_exp2f(xw.z * LOG2E);                     \
        xv[jt][3] = __builtin_amdgcn_exp2f(xw.w * LOG2E);                     \
    }                                                                         \
    if (DOPF) {                                                               \
        int tp = (TPF); if (tp > 511) tp = 511;                               \
        _Pragma("unroll") for (int jt = 0; jt < 8; ++jt)                      \
            xbf[SLOT][jt] = emf4[8192 * tp + lb + 4 * jt];                    \
    }                                                                         \
    float vv[8][4];                                                           \
    _Pragma("unroll") for (int jt = 0; jt < 8; ++jt)                          \
        _Pragma("unroll") for (int r = 0; r < 4; ++r)                         \
            vv[jt][r] = ac[jt][r] * xv[jt][r];                                \
    if (RN) {                                                                 \
        float mx = vv[0][0];                                                  \
        _Pragma("unroll") for (int jt = 0; jt < 8; ++jt)                      \
            _Pragma("unroll") for (int r = 0; r < 4; ++r)                     \
                mx = fmaxf(mx, vv[jt][r]);                                    \
        mx = fmaxf(mx, __shfl_xor(mx, 16));                                   \
        mx = fmaxf(mx, __shfl_xor(mx, 32));                                   \
        int Ee = (__float_as_int(mx) >> 23) & 0xFF;                           \
        if (Ee > 254) Ee = 254;                                               \
        ls2 += Ee - 127;                                                      \
        float scl = __int_as_float((254 - Ee) << 23);                         \
        _Pragma("unroll") for (int jt = 0; jt < 8; ++jt)                      \
            _Pragma("unroll") for (int r = 0; r < 4; ++r)                     \
                vv[jt][r] *= scl;                                             \
    }                                                                         \
    if (LAST) {                                                               \
        fin = 0.f;                                                            \
        _Pragma("unroll") for (int jt = 0; jt < 8; ++jt)                      \
            fin += (vv[jt][0] + vv[jt][1]) + (vv[jt][2] + vv[jt][3]);         \
    } else {                                                                  \
        _Pragma("unroll") for (int ch = 0; ch < 4; ++ch) {                    \
            Bf[ch][0] = packbf2(vv[2*ch][0],     vv[2*ch][1]);                \
            Bf[ch][1] = packbf2(vv[2*ch][2],     vv[2*ch][3]);                \
            Bf[ch][2] = packbf2(vv[2*ch + 1][0], vv[2*ch + 1][1]);            \
            Bf[ch][3] = packbf2(vv[2*ch + 1][2], vv[2*ch + 1][3]);            \
        }                                                                     \
    }                                                                         \
} while (0)

__global__ __launch_bounds__(64, 1) void crf_scan_bf16_kernel(
    const float* __restrict__ emit,
    const float* __restrict__ Tm,
    float* __restrict__ scan_part)
{
    const int gb = blockIdx.x;
    const int l  = threadIdx.x;
    const int b  = l & 15;
    const int g  = l >> 4;
    const int bg = gb * 16 + b;
    const int lb = 32 * bg + g;

    const float4* emf4 = (const float4*)emit;
    const f32x4 zero4 = {0.f, 0.f, 0.f, 0.f};

    u32x4 Afr[4][8];
#pragma unroll
    for (int ch = 0; ch < 4; ++ch)
#pragma unroll
        for (int p = 0; p < 4; ++p) {
            const int e0 = 2 * p, e1 = 2 * p + 1;
            const int jp0 = 32 * ch + 16 * (e0 >> 2) + 4 * g + (e0 & 3);
            const int jp1 = 32 * ch + 16 * (e1 >> 2) + 4 * g + (e1 & 3);
#pragma unroll
            for (int jt = 0; jt < 8; ++jt) {
                float a0 = __builtin_amdgcn_exp2f(Tm[jp0 * 128 + 16 * jt + b] * LOG2E);
                float a1 = __builtin_amdgcn_exp2f(Tm[jp1 * 128 + 16 * jt + b] * LOG2E);
                Afr[ch][jt][p] = packbf2(a0, a1);
            }
        }

    u32x4 Bf[4];
    {
        float x0[8][4];
#pragma unroll
        for (int jt = 0; jt < 8; ++jt) {
            float4 e = emf4[lb + 4 * jt];
            x0[jt][0] = __builtin_amdgcn_exp2f(e.x * LOG2E);
            x0[jt][1] = __builtin_amdgcn_exp2f(e.y * LOG2E);
            x0[jt][2] = __builtin_amdgcn_exp2f(e.z * LOG2E);
            x0[jt][3] = __builtin_amdgcn_exp2f(e.w * LOG2E);
        }
#pragma unroll
        for (int ch = 0; ch < 4; ++ch) {
            Bf[ch][0] = packbf2(x0[2 * ch][0],     x0[2 * ch][1]);
            Bf[ch][1] = packbf2(x0[2 * ch][2],     x0[2 * ch][3]);
            Bf[ch][2] = packbf2(x0[2 * ch + 1][0], x0[2 * ch + 1][1]);
            Bf[ch][3] = packbf2(x0[2 * ch + 1][2], x0[2 * ch + 1][3]);
        }
    }

    float4 xbf[4][8];
#pragma unroll
    for (int k = 0; k < 4; ++k)
#pragma unroll
        for (int jt = 0; jt < 8; ++jt)
            xbf[k][jt] = emf4[8192 * (1 + k) + lb + 4 * jt];

    int ls2 = 0;
    float fin = 0.f;

#pragma unroll 1
    for (int grp = 0; grp < 63; ++grp) {
        const int t0 = 1 + 8 * grp;
        STEPB(0, t0 + 4,  1, 0, 0);
        STEPB(1, t0 + 5,  1, 0, 0);
        STEPB(2, t0 + 6,  1, 0, 0);
        STEPB(3, t0 + 7,  1, 0, 0);
        STEPB(0, t0 + 8,  1, 0, 0);
        STEPB(1, t0 + 9,  1, 0, 0);
        STEPB(2, t0 + 10, 1, 0, 0);
        STEPB(3, t0 + 11, 1, 1, 0);
    }
    STEPB(0, 509, 1, 0, 0);
    STEPB(1, 510, 1, 0, 0);
    STEPB(2, 511, 1, 0, 0);
    STEPB(3, 0,   0, 0, 0);
    STEPB(0, 0,   0, 0, 0);
    STEPB(1, 0,   0, 0, 0);
    STEPB(2, 0,   0, 0, 1);

    fin += __shfl_xor(fin, 16);
    fin += __shfl_xor(fin, 32);
    if (l < 16)
        scan_part[gb * 16 + l] = ((float)ls2 + __log2f(fin)) * LN2F;
}

// ================= gold + final =================
__global__ __launch_bounds__(256) void crf_gold_kernel(
    const float* __restrict__ emit, const float* __restrict__ Tm,
    const int* __restrict__ labels, const int* __restrict__ startp,
    float* __restrict__ gold_part)
{
    const int b = blockIdx.x, tid = threadIdx.x;
    __shared__ int lab[512];
    __shared__ float r[4];
    lab[tid]       = labels[b * 512 + tid];
    lab[tid + 256] = labels[b * 512 + tid + 256];
    __syncthreads();
    float s = 0.f;
    {
        int y0 = lab[tid];
        int p0 = (tid == 0) ? startp[0] : lab[tid - 1];
        s += emit[((size_t)tid * 256 + b) * 128 + y0] + Tm[p0 * 128 + y0];
        int t1 = tid + 256;
        int y1 = lab[t1];
        int p1 = lab[t1 - 1];
        s += emit[((size_t)t1 * 256 + b) * 128 + y1] + Tm[p1 * 128 + y1];
    }
#pragma unroll
    for (int off = 1; off < 64; off <<= 1) s += __shfl_xor(s, off);
    if ((tid & 63) == 0) r[tid >> 6] = s;
    __syncthreads();
    if (tid == 0) gold_part[b] = (r[0] + r[1]) + (r[2] + r[3]);
}

__global__ __launch_bounds__(256) void crf_final_kernel(
    const float* __restrict__ scan_part, const float* __restrict__ gold_part,
    float* __restrict__ out)
{
    const int tid = threadIdx.x;
    __shared__ float r[4];
    float v = scan_part[tid] - gold_part[tid];
#pragma unroll
    for (int off = 1; off < 64; off <<= 1) v += __shfl_xor(v, off);
    if ((tid & 63) == 0) r[tid >> 6] = v;
    __syncthreads();
    if (tid == 0) out[0] = (r[0] + r[1]) + (r[2] + r[3]);
}

extern "C" void kernel_launch(void* const* d_in, const int* in_sizes, int n_in,
                              void* d_out, int out_size, void* d_ws, size_t ws_size,
                              hipStream_t stream) {
    const float* emit   = (const float*)d_in[0];
    const float* Tm     = (const float*)d_in[1];
    const int*   labels = (const int*)d_in[2];
    const int*   startp = (const int*)d_in[3];

    const size_t yx_bytes = (size_t)2 * 32 * 256 * 128 * 4;   // 8,388,608
    const size_t Ls_bytes = (size_t)2 * 32 * 256 * 4;         // 65,536

    if (ws_size >= yx_bytes + Ls_bytes + 4096) {
        float* yx        = (float*)d_ws;
        int*   Ls        = (int*)((char*)d_ws + yx_bytes);
        float* scan_part = (float*)((char*)d_ws + yx_bytes + Ls_bytes);
        float* gold_part = scan_part + 256;
        crf_chunk_kernel  <<<1024, 64, 0, stream>>>(emit, Tm, yx, Ls);
        crf_gold_kernel   <<<256, 256, 0, stream>>>(emit, Tm, labels, startp, gold_part);
        crf_combine_kernel<<<256, 64, 0, stream>>>(emit, yx, Ls, scan_part);
        crf_final_kernel  <<<1, 256, 0, stream>>>(scan_part, gold_part, (float*)d_out);
    } else {
        float* scan_part = (float*)d_ws;
        float* gold_part = scan_part + 256;
        crf_scan_bf16_kernel<<<16, 64, 0, stream>>>(emit, Tm, scan_part);
        crf_gold_kernel<<<256, 256, 0, stream>>>(emit, Tm, labels, startp, gold_part);
        crf_final_kernel<<<1, 256, 0, stream>>>(scan_part, gold_part, (float*)d_out);
    }
}